// Round 1
// baseline (155909.326 us; speedup 1.0000x reference)
//
#include <hip/hip_runtime.h>
#include <math.h>

#define B 256
#define T 512
#define H 1024
#define TH 3072
#define CODE 3

#define BM 32   // batch rows per block
#define JT 32   // j columns (gate triples) per block
#define KC 256  // k chunk staged in LDS

__device__ __forceinline__ float sigmoidf_(float x) { return 1.0f / (1.0f + expf(-x)); }

// One fused GRU step. Computes h_next = GRUCell(x_t, h_prev).
// Encoder (DEC=false): x_t[b] = input[b*T + t]  (xin = input, I=1)
// Decoder (DEC=true):  x_t[b] = (t==0) ? 0 : dot(h_prev[b,:], Wout) + bout
//                      and writes x_t to output[b][t-1] (blocks gj==0) for t>=1.
template <bool DEC>
__global__ __launch_bounds__(256) void gru_step(
    const float* __restrict__ hPrev, float* __restrict__ hNext,
    const float* __restrict__ Wih,   // [3H] (I==1)
    const float* __restrict__ Whh,   // [3H][H]
    const float* __restrict__ bih, const float* __restrict__ bhh,
    const float* __restrict__ xin,   // enc: input [B,T]; dec: Wout [H]
    const float* __restrict__ boutp, // dec only: bout [1]
    float* __restrict__ outCol,      // dec only: output base [B,T]
    int t)
{
    __shared__ float h_s[BM][KC + 4];  // +4 floats pad: keeps rows 16B-aligned, breaks bank stride
    __shared__ float xred[8][BM];
    __shared__ float x_s[BM];

    const int tid = threadIdx.x;
    const int bb = tid & 31;   // batch row within tile
    const int jj = tid >> 5;   // 0..7
    const int gj = blockIdx.x & 31;
    const int gb = blockIdx.x >> 5;
    const int b0 = gb * BM;
    const int j0 = gj * JT;

    float acc[12];
#pragma unroll
    for (int i = 0; i < 12; ++i) acc[i] = 0.f;
    float xpart = 0.f;

    for (int kc = 0; kc < H; kc += KC) {
        __syncthreads();
        // stage h chunk [32 x 256] floats; fully coalesced 1KB/wave loads
#pragma unroll
        for (int i = 0; i < 8; ++i) {
            int idx = tid + i * 256;   // float4 index, 0..2047
            int r = idx >> 6;          // 64 float4 per row
            int c = idx & 63;
            ((float4*)&h_s[r][0])[c] =
                ((const float4*)(hPrev + (size_t)(b0 + r) * H + kc))[c];
        }
        __syncthreads();

        if (DEC) {
            // partial of x = dot(h_prev[b,:], Wout): thread (bb,jj) covers 32 k's
            float p = 0.f;
            const float* Wo = xin + kc;
            for (int k = jj * 32; k < jj * 32 + 32; ++k) p += h_s[bb][k] * Wo[k];
            xpart += p;
        }

        // 12 row pointers: j = j0 + jj + 8q, gates r/z/n
        const float4* Wr[12];
#pragma unroll
        for (int q = 0; q < 4; ++q)
#pragma unroll
            for (int g = 0; g < 3; ++g)
                Wr[q * 3 + g] =
                    (const float4*)(Whh + ((size_t)g * H + (j0 + jj + 8 * q)) * H + kc);

        const float4* hs4 = (const float4*)&h_s[bb][0];
        for (int k4 = 0; k4 < KC / 4; ++k4) {
            float4 hv = hs4[k4];
#pragma unroll
            for (int i = 0; i < 12; ++i) {
                float4 w = Wr[i][k4];
                acc[i] += w.x * hv.x + w.y * hv.y + w.z * hv.z + w.w * hv.w;
            }
        }
    }

    float xv;
    if (DEC) {
        xred[jj][bb] = xpart;
        __syncthreads();
        if (jj == 0) {
            float s = 0.f;
#pragma unroll
            for (int q = 0; q < 8; ++q) s += xred[q][bb];
            x_s[bb] = (t == 0) ? 0.f : (s + boutp[0]);
        }
        __syncthreads();
        xv = x_s[bb];
        if (t > 0 && gj == 0 && jj == 0)
            outCol[(size_t)(b0 + bb) * T + (t - 1)] = x_s[bb];
    } else {
        xv = xin[(size_t)(b0 + bb) * T + t];
    }

#pragma unroll
    for (int q = 0; q < 4; ++q) {
        int j = j0 + jj + 8 * q;
        float gr = acc[q * 3 + 0] + bhh[j];
        float gz = acc[q * 3 + 1] + bhh[H + j];
        float gn = acc[q * 3 + 2] + bhh[2 * H + j];
        float ir = xv * Wih[j] + bih[j];
        float iz = xv * Wih[H + j] + bih[H + j];
        float in_ = xv * Wih[2 * H + j] + bih[2 * H + j];
        float r = sigmoidf_(ir + gr);
        float z = sigmoidf_(iz + gz);
        float n = tanhf(in_ + r * gn);
        float hOld = hPrev[(size_t)(b0 + bb) * H + j];
        hNext[(size_t)(b0 + bb) * H + j] = (1.f - z) * n + z * hOld;
    }
}

// features = sigmoid(hT @ Wenc.T + benc) -> d_out[1..]; h0 = features @ Wdec.T + bdec
__global__ __launch_bounds__(256) void bottleneck(
    const float* __restrict__ hT, const float* __restrict__ Wenc,
    const float* __restrict__ benc, const float* __restrict__ Wdec,
    const float* __restrict__ bdec, float* __restrict__ featOut,
    float* __restrict__ h0)
{
    int b = blockIdx.x, tid = threadIdx.x;
    const float4* hr = (const float4*)(hT + (size_t)b * H);
    const float4* w0 = (const float4*)(Wenc);
    const float4* w1 = (const float4*)(Wenc + H);
    const float4* w2 = (const float4*)(Wenc + 2 * H);
    float4 hv = hr[tid], a0 = w0[tid], a1 = w1[tid], a2 = w2[tid];
    float p0 = hv.x * a0.x + hv.y * a0.y + hv.z * a0.z + hv.w * a0.w;
    float p1 = hv.x * a1.x + hv.y * a1.y + hv.z * a1.z + hv.w * a1.w;
    float p2 = hv.x * a2.x + hv.y * a2.y + hv.z * a2.z + hv.w * a2.w;
#pragma unroll
    for (int off = 32; off; off >>= 1) {
        p0 += __shfl_down(p0, off);
        p1 += __shfl_down(p1, off);
        p2 += __shfl_down(p2, off);
    }
    __shared__ float wred[3][4];
    __shared__ float feats[3];
    if ((tid & 63) == 0) {
        wred[0][tid >> 6] = p0; wred[1][tid >> 6] = p1; wred[2][tid >> 6] = p2;
    }
    __syncthreads();
    if (tid < 3) {
        float s = wred[tid][0] + wred[tid][1] + wred[tid][2] + wred[tid][3];
        float f = 1.f / (1.f + expf(-(s + benc[tid])));
        feats[tid] = f;
        featOut[b * CODE + tid] = f;
    }
    __syncthreads();
    float f0 = feats[0], f1 = feats[1], f2 = feats[2];
#pragma unroll
    for (int i = 0; i < 4; ++i) {
        int j = tid + i * 256;
        h0[(size_t)b * H + j] =
            f0 * Wdec[j * 3 + 0] + f1 * Wdec[j * 3 + 1] + f2 * Wdec[j * 3 + 2] + bdec[j];
    }
}

// output[:, T-1] = hFin @ Wout.T + bout
__global__ __launch_bounds__(256) void finalize_out(
    const float* __restrict__ hFin, const float* __restrict__ Wout,
    const float* __restrict__ boutp, float* __restrict__ outp)
{
    int b = blockIdx.x, tid = threadIdx.x;
    const float4* hr = (const float4*)(hFin + (size_t)b * H);
    const float4* wr = (const float4*)Wout;
    float4 hv = hr[tid], wv = wr[tid];
    float p = hv.x * wv.x + hv.y * wv.y + hv.z * wv.z + hv.w * wv.w;
#pragma unroll
    for (int off = 32; off; off >>= 1) p += __shfl_down(p, off);
    __shared__ float ws[4];
    if ((tid & 63) == 0) ws[tid >> 6] = p;
    __syncthreads();
    if (tid == 0) outp[(size_t)b * T + (T - 1)] = ws[0] + ws[1] + ws[2] + ws[3] + boutp[0];
}

__global__ __launch_bounds__(256) void loss_partial(
    const float* __restrict__ input, const float* __restrict__ outp,
    float* __restrict__ partial)
{
    int idx = blockIdx.x * blockDim.x + threadIdx.x;
    float s = 0.f;
    for (int i = idx; i < B * T; i += gridDim.x * blockDim.x) {
        float d = input[i] - outp[i];
        s += d * d;
    }
#pragma unroll
    for (int off = 32; off; off >>= 1) s += __shfl_down(s, off);
    __shared__ float ws[4];
    if ((threadIdx.x & 63) == 0) ws[threadIdx.x >> 6] = s;
    __syncthreads();
    if (threadIdx.x == 0) partial[blockIdx.x] = ws[0] + ws[1] + ws[2] + ws[3];
}

__global__ __launch_bounds__(256) void loss_final(
    const float* __restrict__ partial, float* __restrict__ loss)
{
    int tid = threadIdx.x;
    float s = partial[tid];
#pragma unroll
    for (int off = 32; off; off >>= 1) s += __shfl_down(s, off);
    __shared__ float ws[4];
    if ((tid & 63) == 0) ws[tid >> 6] = s;
    __syncthreads();
    if (tid == 0) loss[0] = (ws[0] + ws[1] + ws[2] + ws[3]) * (1.0f / (float)(B * T));
}

extern "C" void kernel_launch(void* const* d_in, const int* in_sizes, int n_in,
                              void* d_out, int out_size, void* d_ws, size_t ws_size,
                              hipStream_t stream) {
    const float* input = (const float*)d_in[0];
    const float* h_init = (const float*)d_in[1];
    const float* Wih_e = (const float*)d_in[2];
    const float* Whh_e = (const float*)d_in[3];
    const float* bih_e = (const float*)d_in[4];
    const float* bhh_e = (const float*)d_in[5];
    const float* Wenc  = (const float*)d_in[6];
    const float* benc  = (const float*)d_in[7];
    const float* Wdec  = (const float*)d_in[8];
    const float* bdec  = (const float*)d_in[9];
    const float* Wih_d = (const float*)d_in[10];
    const float* Whh_d = (const float*)d_in[11];
    const float* bih_d = (const float*)d_in[12];
    const float* bhh_d = (const float*)d_in[13];
    const float* Wout  = (const float*)d_in[14];
    const float* bout  = (const float*)d_in[15];

    float* out = (float*)d_out;
    float* lossp = out;                    // [1]
    float* feat = out + 1;                 // [B*CODE]
    float* outp = out + 1 + B * CODE;      // [B*T]

    float* hA = (float*)d_ws;
    float* hB = hA + (size_t)B * H;
    float* partial = hB + (size_t)B * H;   // [256]

    dim3 blk(256), grid(256);

    // ---- encoder ----
    const float* hp = h_init;
    float* hn = hA;
    for (int t = 0; t < T; ++t) {
        gru_step<false><<<grid, blk, 0, stream>>>(hp, hn, Wih_e, Whh_e, bih_e, bhh_e,
                                                  input, nullptr, nullptr, t);
        hp = hn;
        hn = (hn == hA) ? hB : hA;
    }

    // ---- bottleneck: features + h0 (into hn) ----
    bottleneck<<<B, 256, 0, stream>>>(hp, Wenc, benc, Wdec, bdec, feat, hn);
    hp = hn;
    hn = (hp == hA) ? hB : hA;

    // ---- decoder ----
    for (int t = 0; t < T; ++t) {
        gru_step<true><<<grid, blk, 0, stream>>>(hp, hn, Wih_d, Whh_d, bih_d, bhh_d,
                                                 Wout, bout, outp, t);
        hp = hn;
        hn = (hn == hA) ? hB : hA;
    }

    finalize_out<<<B, 256, 0, stream>>>(hp, Wout, bout, outp);
    loss_partial<<<256, 256, 0, stream>>>(input, outp, partial);
    loss_final<<<1, 256, 0, stream>>>(partial, lossp);
}

// Round 2
// 18358.728 us; speedup vs baseline: 8.4924x; 8.4924x over previous
//
#include <hip/hip_runtime.h>
#include <math.h>

#define B 256
#define T 512
#define H 1024
#define CODE 3

typedef _Float16 f16x8 __attribute__((ext_vector_type(8)));
typedef _Float16 f16x4 __attribute__((ext_vector_type(4)));
typedef float f32x4 __attribute__((ext_vector_type(4)));

__device__ __forceinline__ float sigmoidf_(float x) { return 1.0f / (1.0f + expf(-x)); }

// ---- fp32 -> f16 conversion (vectorized float4 -> half4) ----
__global__ __launch_bounds__(256) void cvt_f32_f16(const float* __restrict__ s,
                                                   _Float16* __restrict__ d, int n4) {
    int i = blockIdx.x * 256 + threadIdx.x;
    if (i < n4) {
        float4 v = ((const float4*)s)[i];
        f16x4 o;
        o[0] = (_Float16)v.x; o[1] = (_Float16)v.y;
        o[2] = (_Float16)v.z; o[3] = (_Float16)v.w;
        ((f16x4*)d)[i] = o;
    }
}

// ---- One fused GRU step via MFMA ----
// Grid: 256 blocks = 8 b-tiles x 32 j-tiles. 512 threads = 8 waves.
// Wave w: quadrant q=w&3 -> (mp=q>>1, np=q&1), K-half kh=w>>2.
// Each wave: 3 gate fragments [16m x 16n] over K-half, fp32 acc; LDS reduce of
// K-halves; lane-local GRU epilogue (r,z,n for same (b,j) live in same lane).
// Decoder: x_t read from xpart[t&1] (+bout); writes hNext.Wout partials to
// xpart[(t+1)&1] via deterministic LDS reduce; writes output[b][t-1].
template <bool DEC>
__global__ __launch_bounds__(512) void gru_step_mfma(
    const float* __restrict__ hPrev, float* __restrict__ hNext,
    const _Float16* __restrict__ h16Prev, _Float16* __restrict__ h16Next,
    const _Float16* __restrict__ Whh16,
    const float* __restrict__ Wih, const float* __restrict__ bih,
    const float* __restrict__ bhh,
    const float* __restrict__ xin,   // encoder: input [B,T]
    const float* __restrict__ Wout,  // decoder: [H]
    const float* __restrict__ boutp, // decoder: [1]
    float* __restrict__ xpart,       // decoder: [2][32][256]
    float* __restrict__ outp,        // decoder: output [B,T]
    int t)
{
    __shared__ float red[4][3][64][4];   // 12 KB: K-half reduce
    __shared__ float xv_s[32];
    __shared__ float xr[32][33];         // x-partial reduce (+1 pad)

    const int tid = threadIdx.x;
    const int lane = tid & 63;
    const int w = tid >> 6;
    const int q = w & 3, mp = q >> 1, np = q & 1, kh = w >> 2;
    const int bt = blockIdx.x >> 5, jt = blockIdx.x & 31;
    const int b0 = bt * 32, j0 = jt * 32;
    const int r16 = lane & 15, kg = lane >> 4;

    // A: h16[b0+mp*16+r16][k], B(gate g): Whh16[g*H + j0+np*16+r16][k]
    const _Float16* Aq = h16Prev + (size_t)(b0 + mp * 16 + r16) * H + kh * 512 + kg * 8;
    const _Float16* Bq = Whh16 + (size_t)(j0 + np * 16 + r16) * H + kh * 512 + kg * 8;

    f32x4 aR = {0.f, 0.f, 0.f, 0.f};
    f32x4 aZ = {0.f, 0.f, 0.f, 0.f};
    f32x4 aN = {0.f, 0.f, 0.f, 0.f};

#pragma unroll 4
    for (int kc = 0; kc < 16; ++kc) {
        int ko = kc * 32;
        f16x8 a  = *(const f16x8*)(Aq + ko);
        f16x8 br = *(const f16x8*)(Bq + ko);
        f16x8 bz = *(const f16x8*)(Bq + 1048576 + ko);   // +H*H
        f16x8 bn = *(const f16x8*)(Bq + 2097152 + ko);   // +2*H*H
        aR = __builtin_amdgcn_mfma_f32_16x16x32_f16(a, br, aR, 0, 0, 0);
        aZ = __builtin_amdgcn_mfma_f32_16x16x32_f16(a, bz, aZ, 0, 0, 0);
        aN = __builtin_amdgcn_mfma_f32_16x16x32_f16(a, bn, aN, 0, 0, 0);
    }

    // decoder: gather x_t for this block's 32 batch rows (sum 32 j-tile partials)
    if (DEC) {
        if (tid < 32) {
            float s = 0.f;
            if (t > 0) {
                const float* xp = xpart + (t & 1) * 8192 + (b0 + tid);
#pragma unroll
                for (int j = 0; j < 32; ++j) s += xp[j * 256];
                s += boutp[0];
            }
            xv_s[tid] = s;
            if (t > 0 && jt == 0) outp[(size_t)(b0 + tid) * T + (t - 1)] = s;
        }
    }

    if (kh == 1) {
#pragma unroll
        for (int i = 0; i < 4; ++i) {
            red[q][0][lane][i] = aR[i];
            red[q][1][lane][i] = aZ[i];
            red[q][2][lane][i] = aN[i];
        }
    }
    __syncthreads();

    if (kh == 0) {
#pragma unroll
        for (int i = 0; i < 4; ++i) {
            aR[i] += red[q][0][lane][i];
            aZ[i] += red[q][1][lane][i];
            aN[i] += red[q][2][lane][i];
        }
        const int j = j0 + np * 16 + r16;
        const float bh_r = bhh[j], bh_z = bhh[H + j], bh_n = bhh[2 * H + j];
        const float wi_r = Wih[j], wi_z = Wih[H + j], wi_n = Wih[2 * H + j];
        const float bi_r = bih[j], bi_z = bih[H + j], bi_n = bih[2 * H + j];
        const float wo = DEC ? Wout[j] : 0.f;
#pragma unroll
        for (int reg = 0; reg < 4; ++reg) {
            const int brow = mp * 16 + kg * 4 + reg;
            const int b = b0 + brow;
            const float xv = DEC ? xv_s[brow] : xin[(size_t)b * T + t];
            const float r = sigmoidf_(xv * wi_r + bi_r + aR[reg] + bh_r);
            const float z = sigmoidf_(xv * wi_z + bi_z + aZ[reg] + bh_z);
            const float n = tanhf(xv * wi_n + bi_n + r * (aN[reg] + bh_n));
            const float hOld = hPrev[(size_t)b * H + j];
            const float hNew = (1.f - z) * n + z * hOld;
            hNext[(size_t)b * H + j] = hNew;
            h16Next[(size_t)b * H + j] = (_Float16)hNew;
            if (DEC) xr[brow][np * 16 + r16] = hNew * wo;
        }
    }

    if (DEC) {
        __syncthreads();
        if (tid < 32) {
            float s = 0.f;
#pragma unroll
            for (int c = 0; c < 32; ++c) s += xr[tid][c];
            xpart[((t + 1) & 1) * 8192 + jt * 256 + (b0 + tid)] = s;
        }
    }
}

// features = sigmoid(hT @ Wenc.T + benc) -> feat; h0 = features @ Wdec.T + bdec (f32 + f16)
__global__ __launch_bounds__(256) void bottleneck(
    const float* __restrict__ hT, const float* __restrict__ Wenc,
    const float* __restrict__ benc, const float* __restrict__ Wdec,
    const float* __restrict__ bdec, float* __restrict__ featOut,
    float* __restrict__ h0, _Float16* __restrict__ h016)
{
    int b = blockIdx.x, tid = threadIdx.x;
    const float4* hr = (const float4*)(hT + (size_t)b * H);
    const float4* w0 = (const float4*)(Wenc);
    const float4* w1 = (const float4*)(Wenc + H);
    const float4* w2 = (const float4*)(Wenc + 2 * H);
    float4 hv = hr[tid], a0 = w0[tid], a1 = w1[tid], a2 = w2[tid];
    float p0 = hv.x * a0.x + hv.y * a0.y + hv.z * a0.z + hv.w * a0.w;
    float p1 = hv.x * a1.x + hv.y * a1.y + hv.z * a1.z + hv.w * a1.w;
    float p2 = hv.x * a2.x + hv.y * a2.y + hv.z * a2.z + hv.w * a2.w;
#pragma unroll
    for (int off = 32; off; off >>= 1) {
        p0 += __shfl_down(p0, off);
        p1 += __shfl_down(p1, off);
        p2 += __shfl_down(p2, off);
    }
    __shared__ float wred[3][4];
    __shared__ float feats[3];
    if ((tid & 63) == 0) {
        wred[0][tid >> 6] = p0; wred[1][tid >> 6] = p1; wred[2][tid >> 6] = p2;
    }
    __syncthreads();
    if (tid < 3) {
        float s = wred[tid][0] + wred[tid][1] + wred[tid][2] + wred[tid][3];
        float f = 1.f / (1.f + expf(-(s + benc[tid])));
        feats[tid] = f;
        featOut[b * CODE + tid] = f;
    }
    __syncthreads();
    float f0 = feats[0], f1 = feats[1], f2 = feats[2];
#pragma unroll
    for (int i = 0; i < 4; ++i) {
        int jj = tid + i * 256;
        float v = f0 * Wdec[jj * 3 + 0] + f1 * Wdec[jj * 3 + 1] + f2 * Wdec[jj * 3 + 2] + bdec[jj];
        h0[(size_t)b * H + jj] = v;
        h016[(size_t)b * H + jj] = (_Float16)v;
    }
}

// output[:, T-1] = sum of xpart slot0 + bout  (step T-1 wrote slot (T)&1 == 0)
__global__ __launch_bounds__(256) void finalize_out(
    const float* __restrict__ xpart, const float* __restrict__ boutp,
    float* __restrict__ outp)
{
    int b = threadIdx.x;
    float s = 0.f;
#pragma unroll
    for (int jt = 0; jt < 32; ++jt) s += xpart[jt * 256 + b];
    outp[(size_t)b * T + (T - 1)] = s + boutp[0];
}

__global__ __launch_bounds__(256) void loss_partial(
    const float* __restrict__ input, const float* __restrict__ outp,
    float* __restrict__ partial)
{
    int idx = blockIdx.x * blockDim.x + threadIdx.x;
    float s = 0.f;
    for (int i = idx; i < B * T; i += gridDim.x * blockDim.x) {
        float d = input[i] - outp[i];
        s += d * d;
    }
#pragma unroll
    for (int off = 32; off; off >>= 1) s += __shfl_down(s, off);
    __shared__ float ws[4];
    if ((threadIdx.x & 63) == 0) ws[threadIdx.x >> 6] = s;
    __syncthreads();
    if (threadIdx.x == 0) partial[blockIdx.x] = ws[0] + ws[1] + ws[2] + ws[3];
}

__global__ __launch_bounds__(256) void loss_final(
    const float* __restrict__ partial, float* __restrict__ loss)
{
    int tid = threadIdx.x;
    float s = partial[tid];
#pragma unroll
    for (int off = 32; off; off >>= 1) s += __shfl_down(s, off);
    __shared__ float ws[4];
    if ((tid & 63) == 0) ws[tid >> 6] = s;
    __syncthreads();
    if (tid == 0) loss[0] = (ws[0] + ws[1] + ws[2] + ws[3]) * (1.0f / (float)(B * T));
}

extern "C" void kernel_launch(void* const* d_in, const int* in_sizes, int n_in,
                              void* d_out, int out_size, void* d_ws, size_t ws_size,
                              hipStream_t stream) {
    const float* input = (const float*)d_in[0];
    const float* h_init = (const float*)d_in[1];
    const float* Wih_e = (const float*)d_in[2];
    const float* Whh_e = (const float*)d_in[3];
    const float* bih_e = (const float*)d_in[4];
    const float* bhh_e = (const float*)d_in[5];
    const float* Wenc  = (const float*)d_in[6];
    const float* benc  = (const float*)d_in[7];
    const float* Wdec  = (const float*)d_in[8];
    const float* bdec  = (const float*)d_in[9];
    const float* Wih_d = (const float*)d_in[10];
    const float* Whh_d = (const float*)d_in[11];
    const float* bih_d = (const float*)d_in[12];
    const float* bhh_d = (const float*)d_in[13];
    const float* Wout  = (const float*)d_in[14];
    const float* bout  = (const float*)d_in[15];

    float* out = (float*)d_out;
    float* lossp = out;                    // [1]
    float* feat = out + 1;                 // [B*CODE]
    float* outp = out + 1 + B * CODE;      // [B*T]

    // ---- workspace layout ----
    char* ws = (char*)d_ws;
    float* hA = (float*)ws;                          ws += (size_t)B * H * 4;
    float* hB = (float*)ws;                          ws += (size_t)B * H * 4;
    _Float16* h16A = (_Float16*)ws;                  ws += (size_t)B * H * 2;
    _Float16* h16B = (_Float16*)ws;                  ws += (size_t)B * H * 2;
    _Float16* WhhE16 = (_Float16*)ws;                ws += (size_t)3 * H * H * 2;
    _Float16* WhhD16 = (_Float16*)ws;                ws += (size_t)3 * H * H * 2;
    float* xpart = (float*)ws;                       ws += 2 * 32 * 256 * 4;
    float* partial = (float*)ws;                     ws += 256 * 4;

    // ---- weight + h_init conversion ----
    cvt_f32_f16<<<(3 * H * H / 4 + 255) / 256, 256, 0, stream>>>(Whh_e, WhhE16, 3 * H * H / 4);
    cvt_f32_f16<<<(3 * H * H / 4 + 255) / 256, 256, 0, stream>>>(Whh_d, WhhD16, 3 * H * H / 4);
    cvt_f32_f16<<<(B * H / 4 + 255) / 256, 256, 0, stream>>>(h_init, h16B, B * H / 4);

    dim3 blk(512), grid(256);

    // ---- encoder ----
    const float* hp = h_init;  const _Float16* h16p = h16B;
    float* hn = hA;            _Float16* h16n = h16A;
    for (int t = 0; t < T; ++t) {
        gru_step_mfma<false><<<grid, blk, 0, stream>>>(
            hp, hn, h16p, h16n, WhhE16, Wih_e, bih_e, bhh_e,
            input, nullptr, nullptr, nullptr, nullptr, t);
        hp = hn; h16p = h16n;
        if (hn == hA) { hn = hB; h16n = h16B; } else { hn = hA; h16n = h16A; }
    }
    // encoder ends writing hB/h16B (T even)

    // ---- bottleneck: features + h0 -> hA/h16A ----
    bottleneck<<<B, 256, 0, stream>>>(hp, Wenc, benc, Wdec, bdec, feat, hA, h16A);
    hp = hA; h16p = h16A; hn = hB; h16n = h16B;

    // ---- decoder ----
    for (int t = 0; t < T; ++t) {
        gru_step_mfma<true><<<grid, blk, 0, stream>>>(
            hp, hn, h16p, h16n, WhhD16, Wih_d, bih_d, bhh_d,
            nullptr, Wout, bout, xpart, outp, t);
        hp = hn; h16p = h16n;
        if (hn == hA) { hn = hB; h16n = h16B; } else { hn = hA; h16n = h16A; }
    }

    finalize_out<<<1, 256, 0, stream>>>(xpart, bout, outp);
    loss_partial<<<256, 256, 0, stream>>>(input, outp, partial);
    loss_final<<<1, 256, 0, stream>>>(partial, lossp);
}